// Round 10
// baseline (64.551 us; speedup 1.0000x reference)
//
#include <hip/hip_runtime.h>

#define NPTS 32768
#define C 128
#define KNBR 16

typedef __attribute__((ext_vector_type(8))) short short8;
typedef __attribute__((ext_vector_type(4))) float floatx4;
typedef __attribute__((ext_vector_type(4))) int intx4;

__device__ __forceinline__ ushort f2b(float f) {
    union { float f; uint u; } x; x.f = f;
    uint r = (x.u + 0x7fffu + ((x.u >> 16) & 1u)) >> 16;
    return (ushort)r;
}
__device__ __forceinline__ ushort f2h(float f) {
    union { _Float16 h; ushort u; } x; x.h = (_Float16)f; return x.u;
}
__device__ __forceinline__ float h2f(ushort u) {
    union { ushort u; _Float16 h; } x; x.u = u; return (float)x.h;
}
__device__ __forceinline__ short8 pack8(float4 a, float4 b) {
    union { short8 s; uint u[4]; } x;
    x.u[0] = (uint)f2b(a.x) | ((uint)f2b(a.y) << 16);
    x.u[1] = (uint)f2b(a.z) | ((uint)f2b(a.w) << 16);
    x.u[2] = (uint)f2b(b.x) | ((uint)f2b(b.y) << 16);
    x.u[3] = (uint)f2b(b.z) | ((uint)f2b(b.w) << 16);
    return x.s;
}

// ---------------- QKV GEMM, occupancy/MLP-first ----------------
// 1024 blocks x 256 thr; 32-row tile; feats read ONCE (Q,K,V share staged A).
// LDS 9.5KB -> 4 blocks/CU (16 waves/CU). Staging: 4 independent float4 loads
// issued before any pack. W: fp32 fragments from global (L2-resident), packed in-reg.
// Wave wid owns cols [wid*32, wid*32+32) = head wid. int8 word layout (head-pure):
//   word w = wid*8 + (fr>>1), bytes = cols {c, c+16, c+1, c+17}, c = wid*32 + (fr&~1).
__global__ __launch_bounds__(256, 4) void qkv_gemm(
    const float* __restrict__ feats, const float* __restrict__ Wq,
    const float* __restrict__ Wk, const float* __restrict__ Wv,
    unsigned char* __restrict__ q8, unsigned char* __restrict__ kv8,
    ushort* __restrict__ scpack, float* __restrict__ qscale)
{
    __shared__ ushort ldsA[32 * 128];     // 8 KB
    __shared__ float rmax4[3][4][32];     // 1.5 KB
    const int tid = threadIdx.x, lane = tid & 63, wid = tid >> 6;
    const int r0 = blockIdx.x * 32;

    // stage A: 32x128 fp32 -> bf16. All 4 loads issued before packing.
    float4 va[4];
#pragma unroll
    for (int it = 0; it < 4; ++it) {
        const int f = it * 256 + tid;               // float4 id 0..1023
        va[it] = *(const float4*)(feats + (size_t)r0 * 128 + (size_t)f * 4);
    }
#pragma unroll
    for (int it = 0; it < 4; ++it) {
        const int f = it * 256 + tid;
        const int row = f >> 5, slot = (f & 31) >> 1, half = f & 1;
        uint2 o;
        o.x = (uint)f2b(va[it].x) | ((uint)f2b(va[it].y) << 16);
        o.y = (uint)f2b(va[it].z) | ((uint)f2b(va[it].w) << 16);
        *(uint2*)(ldsA + (row * 16 + (slot ^ (row & 7))) * 8 + half * 4) = o;
    }
    __syncthreads();

    const int fr = lane & 15, kb = lane >> 4;

    // A-fragments (reused by all 3 projections)
    short8 af[2][4];
#pragma unroll
    for (int i = 0; i < 2; ++i)
#pragma unroll
        for (int kk = 0; kk < 4; ++kk) {
            const int row = i * 16 + fr;
            const int slot = kk * 4 + kb;
            af[i][kk] = *(const short8*)(ldsA + (row * 16 + (slot ^ (row & 7))) * 8);
        }

    const int boff = (wid * 8 + (fr >> 1)) * 4;

#pragma unroll
    for (int sel = 0; sel < 3; ++sel) {
        const float* W = (sel == 0) ? Wq : (sel == 1) ? Wk : Wv;

        floatx4 acc[2][2];
#pragma unroll
        for (int i = 0; i < 2; ++i)
#pragma unroll
            for (int j = 0; j < 2; ++j) acc[i][j] = (floatx4){0.f, 0.f, 0.f, 0.f};

#pragma unroll
        for (int kk = 0; kk < 4; ++kk) {
            short8 bf[2];
#pragma unroll
            for (int j = 0; j < 2; ++j) {
                const float* wp = W + (size_t)(wid * 32 + j * 16 + fr) * 128 + kk * 32 + kb * 8;
                float4 w0 = *(const float4*)wp;
                float4 w1 = *(const float4*)(wp + 4);
                bf[j] = pack8(w0, w1);
            }
#pragma unroll
            for (int i = 0; i < 2; ++i)
#pragma unroll
                for (int j = 0; j < 2; ++j)
                    acc[i][j] = __builtin_amdgcn_mfma_f32_16x16x32_bf16(af[i][kk], bf[j], acc[i][j], 0, 0, 0);
        }

        // per-row absmax over this wave's 32 cols, then cross-wave via LDS
        float mx[2][4];
#pragma unroll
        for (int i = 0; i < 2; ++i)
#pragma unroll
            for (int r = 0; r < 4; ++r) {
                float m = fmaxf(fabsf(acc[i][0][r]), fabsf(acc[i][1][r]));
                m = fmaxf(m, __shfl_xor(m, 1));
                m = fmaxf(m, __shfl_xor(m, 2));
                m = fmaxf(m, __shfl_xor(m, 4));
                m = fmaxf(m, __shfl_xor(m, 8));
                mx[i][r] = m;
            }
        if (fr == 0) {
#pragma unroll
            for (int i = 0; i < 2; ++i)
#pragma unroll
                for (int r = 0; r < 4; ++r)
                    rmax4[sel][wid][i * 16 + kb * 4 + r] = mx[i][r];
        }
        __syncthreads();

#pragma unroll
        for (int i = 0; i < 2; ++i)
#pragma unroll
            for (int r = 0; r < 4; ++r) {
                const int lr = i * 16 + kb * 4 + r;
                const int nn = r0 + lr;
                float comb = fmaxf(rmax4[sel][0][lr], rmax4[sel][1][lr]);
                comb = fmaxf(comb, rmax4[sel][2][lr]);
                comb = fmaxf(comb, rmax4[sel][3][lr]);
                comb = fmaxf(comb, 1e-20f);
                const float qs = 127.f / comb;
                int b0 = __float2int_rn(acc[i][0][r] * qs);   // col wid*32 + fr
                int b1 = __float2int_rn(acc[i][1][r] * qs);   // col wid*32 + fr + 16
                uint u16 = (uint)(b0 & 0xff) | ((uint)(b1 & 0xff) << 8);
                uint o16 = __shfl_xor(u16, 1);
                if (wid == 0 && fr == 0) {
                    if (sel == 0)      qscale[nn] = comb * (1.f / 127.f);
                    else if (sel == 1) scpack[(size_t)nn * 2]     = f2h(comb * (1.f / 127.f));
                    else               scpack[(size_t)nn * 2 + 1] = f2h(comb * (1.f / 127.f));
                }
                if (!(fr & 1)) {
                    const uint word = u16 | (o16 << 16);
                    if (sel == 0)      *(uint*)(q8  + (size_t)nn * 128 + boff) = word;
                    else if (sel == 1) *(uint*)(kv8 + (size_t)nn * 256 + boff) = word;
                    else               *(uint*)(kv8 + (size_t)nn * 256 + 128 + boff) = word;
                }
            }
    }
}

// ---------------- attention: 1 wave/point, lane = (neighbor kk = l>>2, head h = l&3) ------------
__global__ __launch_bounds__(256, 6) void attn_kernel(
    const unsigned char* __restrict__ q8, const unsigned char* __restrict__ kv8,
    const ushort* __restrict__ scpack, const float* __restrict__ qscale,
    const int* __restrict__ knn, ushort* __restrict__ attn_p)
{
    const int tid = threadIdx.x;
    const int lane = tid & 63;
    const int wp = __builtin_amdgcn_readfirstlane(tid >> 6);
    const int n = blockIdx.x * 4 + wp;

    const int kk = lane >> 2, h = lane & 3;
    const int nb4 = knn[(size_t)n * KNBR + kk];
    const int* kr = knn + (size_t)n * KNBR;

    const unsigned char* krow = kv8 + (size_t)nb4 * 256 + h * 32;
    intx4 k0 = *(const intx4*)(krow);
    intx4 k1 = *(const intx4*)(krow + 16);
    const unsigned char* qrow = q8 + (size_t)n * 128 + h * 32;
    intx4 qq0 = *(const intx4*)(qrow);
    intx4 qq1 = *(const intx4*)(qrow + 16);
    const uint scp = *(const uint*)(scpack + (size_t)nb4 * 2);

    ushort vsh[KNBR];
#pragma unroll
    for (int j = 0; j < KNBR; ++j) {
        const int nbv = kr[j];
        vsh[j] = *(const ushort*)(kv8 + (size_t)nbv * 256 + 128 + lane * 2);
    }

    const float qs6 = qscale[n] * 0.17677669529663687f;

    int dp = 0;
#if __has_builtin(__builtin_amdgcn_sdot4)
#pragma unroll
    for (int i = 0; i < 4; ++i) dp = __builtin_amdgcn_sdot4(qq0[i], k0[i], dp, false);
#pragma unroll
    for (int i = 0; i < 4; ++i) dp = __builtin_amdgcn_sdot4(qq1[i], k1[i], dp, false);
#else
#pragma unroll
    for (int i = 0; i < 4; ++i) {
        uint a = (uint)qq0[i], b = (uint)k0[i];
        dp += (int)(signed char)(a) * (int)(signed char)(b)
            + (int)(signed char)(a >> 8) * (int)(signed char)(b >> 8)
            + (int)(signed char)(a >> 16) * (int)(signed char)(b >> 16)
            + (int)(signed char)(a >> 24) * (int)(signed char)(b >> 24);
        a = (uint)qq1[i]; b = (uint)k1[i];
        dp += (int)(signed char)(a) * (int)(signed char)(b)
            + (int)(signed char)(a >> 8) * (int)(signed char)(b >> 8)
            + (int)(signed char)(a >> 16) * (int)(signed char)(b >> 16)
            + (int)(signed char)(a >> 24) * (int)(signed char)(b >> 24);
    }
#endif

    const float ksc = h2f((ushort)(scp & 0xffff));
    const float vsc = h2f((ushort)(scp >> 16));
    const float sc = (float)dp * ksc * qs6;

    float mxv = sc;
    mxv = fmaxf(mxv, __shfl_xor(mxv, 4));
    mxv = fmaxf(mxv, __shfl_xor(mxv, 8));
    mxv = fmaxf(mxv, __shfl_xor(mxv, 16));
    mxv = fmaxf(mxv, __shfl_xor(mxv, 32));
    const float e = __expf(sc - mxv);
    float sm = e;
    sm += __shfl_xor(sm, 4);
    sm += __shfl_xor(sm, 8);
    sm += __shfl_xor(sm, 16);
    sm += __shfl_xor(sm, 32);
    const float wgt = e * vsc / sm;

    const int h2v = lane >> 4;
    float a0 = 0.f, a1 = 0.f;
#pragma unroll
    for (int j = 0; j < KNBR; ++j) {
        const float w2 = __shfl(wgt, j * 4 + h2v);
        const ushort u = vsh[j];
        a0 += w2 * (float)(signed char)(u & 0xff);
        a1 += w2 * (float)(signed char)(u >> 8);
    }
    // normal channel order: c0 = 32*(lane>>4) + (lane&15), c1 = c0 + 16
    const int cb = 32 * (lane >> 4) + (lane & 15);
    attn_p[(size_t)n * 128 + cb]      = f2b(a0);
    attn_p[(size_t)n * 128 + cb + 16] = f2b(a1);
}

// ---------------- output projection: same occupancy-first structure ----------------
// attn_p is L3-warm (just written); Wo fp32 fragments from global (L2-resident after first touch).
__global__ __launch_bounds__(256, 4) void out_gemm(
    const ushort* __restrict__ A, const float* __restrict__ Wo,
    const float* __restrict__ bias, float* __restrict__ out)
{
    __shared__ ushort ldsA[32 * 128];     // 8 KB
    const int tid = threadIdx.x, lane = tid & 63, wid = tid >> 6;
    const int r0 = blockIdx.x * 32;

    // stage A (bf16 copy), 2 intx4 per thread, issued before LDS writes
    intx4 vb[2];
#pragma unroll
    for (int it = 0; it < 2; ++it) {
        const int f = it * 256 + tid;           // 16B-chunk 0..511
        vb[it] = *(const intx4*)(A + (size_t)r0 * 128 + (size_t)f * 8);
    }
#pragma unroll
    for (int it = 0; it < 2; ++it) {
        const int f = it * 256 + tid;
        const int row = f >> 4, slot = f & 15;
        *(intx4*)(ldsA + (row * 16 + (slot ^ (row & 7))) * 8) = vb[it];
    }
    __syncthreads();

    const int fr = lane & 15, kb = lane >> 4;

    short8 af[2][4];
#pragma unroll
    for (int i = 0; i < 2; ++i)
#pragma unroll
        for (int kk = 0; kk < 4; ++kk) {
            const int row = i * 16 + fr;
            const int slot = kk * 4 + kb;
            af[i][kk] = *(const short8*)(ldsA + (row * 16 + (slot ^ (row & 7))) * 8);
        }

    floatx4 acc[2][2];
#pragma unroll
    for (int i = 0; i < 2; ++i)
#pragma unroll
        for (int j = 0; j < 2; ++j) acc[i][j] = (floatx4){0.f, 0.f, 0.f, 0.f};

#pragma unroll
    for (int kk = 0; kk < 4; ++kk) {
        short8 bf[2];
#pragma unroll
        for (int j = 0; j < 2; ++j) {
            const float* wp = Wo + (size_t)(wid * 32 + j * 16 + fr) * 128 + kk * 32 + kb * 8;
            float4 w0 = *(const float4*)wp;
            float4 w1 = *(const float4*)(wp + 4);
            bf[j] = pack8(w0, w1);
        }
#pragma unroll
        for (int i = 0; i < 2; ++i)
#pragma unroll
            for (int j = 0; j < 2; ++j)
                acc[i][j] = __builtin_amdgcn_mfma_f32_16x16x32_bf16(af[i][kk], bf[j], acc[i][j], 0, 0, 0);
    }

#pragma unroll
    for (int j = 0; j < 2; ++j) {
        const int col = wid * 32 + j * 16 + fr;
        const float bv = bias[col];
#pragma unroll
        for (int i = 0; i < 2; ++i)
#pragma unroll
            for (int r = 0; r < 4; ++r) {
                const int n = r0 + i * 16 + kb * 4 + r;
                out[(size_t)n * 128 + col] = acc[i][j][r] + bv;
            }
    }
}

extern "C" void kernel_launch(void* const* d_in, const int* in_sizes, int n_in,
                              void* d_out, int out_size, void* d_ws, size_t ws_size,
                              hipStream_t stream)
{
    const float* feats = (const float*)d_in[0];
    const int*   knn   = (const int*)d_in[2];
    const float* Wq    = (const float*)d_in[3];
    const float* Wk    = (const float*)d_in[4];
    const float* Wv    = (const float*)d_in[5];
    const float* Wo    = (const float*)d_in[6];
    const float* bo    = (const float*)d_in[7];
    float* out = (float*)d_out;

    ushort* attn_p = (ushort*)d_ws;                                    // N*128 ushort
    unsigned char* q8  = (unsigned char*)(attn_p + (size_t)NPTS * C);  // N*128 B
    unsigned char* kv8 = q8 + (size_t)NPTS * 128;                      // N*256 B
    ushort* scpack = (ushort*)(kv8 + (size_t)NPTS * 256);              // N*2 ushort
    float* qscale  = (float*)(scpack + (size_t)NPTS * 2);              // N floats

    qkv_gemm<<<NPTS / 32, 256, 0, stream>>>(feats, Wq, Wk, Wv,
                                            q8, kv8, scpack, qscale);
    attn_kernel<<<NPTS / 4, 256, 0, stream>>>(q8, kv8, scpack, qscale, knn, attn_p);
    out_gemm<<<NPTS / 32, 256, 0, stream>>>(attn_p, Wo, bo, out);
}

// Round 11
// 49.483 us; speedup vs baseline: 1.3045x; 1.3045x over previous
//
#include <hip/hip_runtime.h>

#define NPTS 32768
#define C 128
#define KNBR 16

typedef __attribute__((ext_vector_type(8))) short short8;
typedef __attribute__((ext_vector_type(4))) float floatx4;
typedef __attribute__((ext_vector_type(4))) int intx4;

__device__ __forceinline__ ushort f2b(float f) {
    union { float f; uint u; } x; x.f = f;
    uint r = (x.u + 0x7fffu + ((x.u >> 16) & 1u)) >> 16;
    return (ushort)r;
}
__device__ __forceinline__ ushort f2h(float f) {
    union { _Float16 h; ushort u; } x; x.h = (_Float16)f; return x.u;
}
__device__ __forceinline__ float h2f(ushort u) {
    union { ushort u; _Float16 h; } x; x.u = u; return (float)x.h;
}

// int8 row permutation (qkv<->attn internal): byte b of word w holds channel col_of(w,b)
__device__ __forceinline__ int col_of(int w, int b) {
    return 64 * (w >> 4) + 32 * ((w >> 3) & 1) + 16 * (b & 1) + 2 * (w & 7) + (b >> 1);
}

// ---------------- prep: feats + all four weights -> plain bf16 ----------------
__global__ __launch_bounds__(256) void prep_all(
    const float* __restrict__ feats, const float* __restrict__ Wq,
    const float* __restrict__ Wk, const float* __restrict__ Wv,
    const float* __restrict__ Wo,
    ushort* __restrict__ feats_b, ushort* __restrict__ wq_b,
    ushort* __restrict__ wk_b, ushort* __restrict__ wv_b, ushort* __restrict__ wo_b)
{
    const int b = blockIdx.x, tid = threadIdx.x;
    const float* src; ushort* dst; size_t base;
    if (b < 2048) { src = feats; dst = feats_b; base = (size_t)b * 2048; }
    else {
        const int wb = b - 2048, wsel = wb >> 3;
        base = (size_t)(wb & 7) * 2048;
        src = (wsel == 0) ? Wq : (wsel == 1) ? Wk : (wsel == 2) ? Wv : Wo;
        dst = (wsel == 0) ? wq_b : (wsel == 1) ? wk_b : (wsel == 2) ? wv_b : wo_b;
    }
    const size_t i = base + (size_t)tid * 8;
    float4 v0 = *(const float4*)(src + i);
    float4 v1 = *(const float4*)(src + i + 4);
    intx4 o;
    o.x = (int)((uint)f2b(v0.x) | ((uint)f2b(v0.y) << 16));
    o.y = (int)((uint)f2b(v0.z) | ((uint)f2b(v0.w) << 16));
    o.z = (int)((uint)f2b(v1.x) | ((uint)f2b(v1.y) << 16));
    o.w = (int)((uint)f2b(v1.z) | ((uint)f2b(v1.w) << 16));
    *(intx4*)(dst + i) = o;
}

// ---------------- MFMA GEMM core (r4-proven): 128x128 tile, K=128, out = A @ W^T ----------------
__device__ __forceinline__ void stage128_b(const ushort* __restrict__ gsrc, ushort* lds, int tid)
{
#pragma unroll
    for (int it = 0; it < 8; ++it) {
        const int f = it * 256 + tid;
        const int row = f >> 4, slot = f & 15;
        intx4 v = *(const intx4*)(gsrc + (size_t)f * 8);
        *(intx4*)(lds + ((row * 16 + (slot ^ (row & 7))) * 8)) = v;
    }
}

__device__ __forceinline__ void gemm_frag_acc(const ushort* ldsA, const ushort* ldsW,
                                              floatx4 acc[4][4], int lane)
{
    const int fr = lane & 15, kb = lane >> 4;
#pragma unroll
    for (int kk = 0; kk < 4; ++kk) {
        const int slot = kk * 4 + kb;
        short8 af[4], bf[4];
#pragma unroll
        for (int i = 0; i < 4; ++i) {
            const int row = i * 16 + fr;
            af[i] = *(const short8*)(ldsA + ((row * 16 + (slot ^ (row & 7))) * 8));
            bf[i] = *(const short8*)(ldsW + ((row * 16 + (slot ^ (row & 7))) * 8));
        }
#pragma unroll
        for (int i = 0; i < 4; ++i)
#pragma unroll
            for (int j = 0; j < 4; ++j)
                acc[i][j] = __builtin_amdgcn_mfma_f32_16x16x32_bf16(af[i], bf[j], acc[i][j], 0, 0, 0);
    }
}

// QKV: grid (NPTS/128, 3). sel=0 -> q8 + qscale; sel=1 -> kv8 k-half + scpack.lo; sel=2 -> v-half + .hi
__global__ __launch_bounds__(256) void qkv_gemm(
    const ushort* __restrict__ A, const ushort* __restrict__ wq_b,
    const ushort* __restrict__ wk_b, const ushort* __restrict__ wv_b,
    unsigned char* __restrict__ q8, unsigned char* __restrict__ kv8,
    ushort* __restrict__ scpack, float* __restrict__ qscale)
{
    __shared__ ushort ldsA[16384];
    __shared__ ushort ldsW[16384];
    __shared__ float rmax[2][128];
    const int tid = threadIdx.x, lane = tid & 63, wid = tid >> 6;
    const int r0 = blockIdx.x * 128, sel = blockIdx.y;
    const ushort* W = (sel == 0) ? wq_b : (sel == 1) ? wk_b : wv_b;

    stage128_b(A + (size_t)r0 * 128, ldsA, tid);
    stage128_b(W, ldsW, tid);
    __syncthreads();

    floatx4 acc[4][4];
#pragma unroll
    for (int i = 0; i < 4; ++i)
#pragma unroll
        for (int j = 0; j < 4; ++j) acc[i][j] = (floatx4){0.f, 0.f, 0.f, 0.f};

    const int wr = (wid >> 1) * 64, wc = (wid & 1) * 64;
    gemm_frag_acc(ldsA + wr * 16 * 8, ldsW + wc * 16 * 8, acc, lane);

    const int fr = lane & 15, kb = lane >> 4;

    float mx[4][4];
#pragma unroll
    for (int i = 0; i < 4; ++i)
#pragma unroll
        for (int r = 0; r < 4; ++r) {
            float m = fabsf(acc[i][0][r]);
            m = fmaxf(m, fabsf(acc[i][1][r]));
            m = fmaxf(m, fabsf(acc[i][2][r]));
            m = fmaxf(m, fabsf(acc[i][3][r]));
            m = fmaxf(m, __shfl_xor(m, 1));
            m = fmaxf(m, __shfl_xor(m, 2));
            m = fmaxf(m, __shfl_xor(m, 4));
            m = fmaxf(m, __shfl_xor(m, 8));
            mx[i][r] = m;
        }
    if (fr == 0) {
#pragma unroll
        for (int i = 0; i < 4; ++i)
#pragma unroll
            for (int r = 0; r < 4; ++r)
                rmax[wc >> 6][wr + i * 16 + kb * 4 + r] = mx[i][r];
    }
    __syncthreads();

    const int boff = ((wc >> 5) + (fr & 1)) * 32 + (fr >> 1) * 4;
#pragma unroll
    for (int i = 0; i < 4; ++i)
#pragma unroll
        for (int r = 0; r < 4; ++r) {
            const int lr = wr + i * 16 + kb * 4 + r;
            const int nn = r0 + lr;
            const float comb = fmaxf(fmaxf(rmax[0][lr], rmax[1][lr]), 1e-20f);
            const float qs = 127.f / comb;
            int b0 = __float2int_rn(acc[i][0][r] * qs);
            int b1 = __float2int_rn(acc[i][1][r] * qs);
            int b2 = __float2int_rn(acc[i][2][r] * qs);
            int b3 = __float2int_rn(acc[i][3][r] * qs);
            uint u_lo = (uint)(b0 & 0xff) | ((uint)(b1 & 0xff) << 8);
            uint u_hi = (uint)(b2 & 0xff) | ((uint)(b3 & 0xff) << 8);
            uint o_lo = __shfl_xor(u_lo, 1);
            uint o_hi = __shfl_xor(u_hi, 1);
            uint word = (fr & 1) ? (o_hi | (u_hi << 16)) : (u_lo | (o_lo << 16));
            if (sel == 0) {
                *(uint*)(q8 + (size_t)nn * 128 + boff) = word;
                if (fr == 0 && wc == 0) qscale[nn] = comb * (1.f / 127.f);
            } else if (sel == 1) {
                *(uint*)(kv8 + (size_t)nn * 256 + boff) = word;
                if (fr == 0 && wc == 0) scpack[(size_t)nn * 2] = f2h(comb * (1.f / 127.f));
            } else {
                *(uint*)(kv8 + (size_t)nn * 256 + 128 + boff) = word;
                if (fr == 0 && wc == 0) scpack[(size_t)nn * 2 + 1] = f2h(comb * (1.f / 127.f));
            }
        }
}

// ---------------- fused attention + output projection ----------------
// 512 blocks x 512 thr (8 waves). Each wave: attn for 8 points, rows -> swizzled LDS (normal
// channel order). Then 64x128 @ Wo^T MFMA from LDS. Saves attn_p global round-trip + a launch.
__global__ __launch_bounds__(512) void fused_attn_out(
    const unsigned char* __restrict__ q8, const unsigned char* __restrict__ kv8,
    const ushort* __restrict__ scpack, const float* __restrict__ qscale,
    const int* __restrict__ knn, const ushort* __restrict__ wo_b,
    const float* __restrict__ bias, float* __restrict__ out)
{
    __shared__ ushort ldsW[16384];   // 128x128 Wo, swizzled
    __shared__ ushort ldsA[8192];    // 64x128 attn rows, swizzled
    const int tid = threadIdx.x, lane = tid & 63, wid = tid >> 6;
    const int p0 = blockIdx.x * 64;

    // stage Wo (2048 16B units, 4/thread)
#pragma unroll
    for (int it = 0; it < 4; ++it) {
        const int f = it * 512 + tid;
        const int row = f >> 4, slot = f & 15;
        intx4 v = *(const intx4*)(wo_b + (size_t)f * 8);
        *(intx4*)(ldsW + ((row * 16 + (slot ^ (row & 7))) * 8)) = v;
    }

    // ---- attention phase: this wave handles points p0 + wid*8 .. +7
    const int kk = lane >> 2, h = lane & 3;
    const int h2v = lane >> 4;
    const int cb = 32 * (lane >> 4) + (lane & 15);   // output channels cb, cb+16

#pragma unroll
    for (int p = 0; p < 8; ++p) {
        const int n = p0 + wid * 8 + p;
        const int* kr = knn + (size_t)n * KNBR;
        const int nb4 = kr[kk];

        const unsigned char* krow = kv8 + (size_t)nb4 * 256 + h * 32;
        intx4 k0 = *(const intx4*)(krow);
        intx4 k1 = *(const intx4*)(krow + 16);
        const unsigned char* qrow = q8 + (size_t)n * 128 + h * 32;
        intx4 qq0 = *(const intx4*)(qrow);
        intx4 qq1 = *(const intx4*)(qrow + 16);
        const uint scp = *(const uint*)(scpack + (size_t)nb4 * 2);

        ushort vsh[KNBR];
#pragma unroll
        for (int j = 0; j < KNBR; ++j) {
            const int nbv = kr[j];
            vsh[j] = *(const ushort*)(kv8 + (size_t)nbv * 256 + 128 + lane * 2);
        }

        const float qs6 = qscale[n] * 0.17677669529663687f;

        int dp = 0;
#if __has_builtin(__builtin_amdgcn_sdot4)
#pragma unroll
        for (int i = 0; i < 4; ++i) dp = __builtin_amdgcn_sdot4(qq0[i], k0[i], dp, false);
#pragma unroll
        for (int i = 0; i < 4; ++i) dp = __builtin_amdgcn_sdot4(qq1[i], k1[i], dp, false);
#else
#pragma unroll
        for (int i = 0; i < 4; ++i) {
            uint a = (uint)qq0[i], b = (uint)k0[i];
            dp += (int)(signed char)(a) * (int)(signed char)(b)
                + (int)(signed char)(a >> 8) * (int)(signed char)(b >> 8)
                + (int)(signed char)(a >> 16) * (int)(signed char)(b >> 16)
                + (int)(signed char)(a >> 24) * (int)(signed char)(b >> 24);
            a = (uint)qq1[i]; b = (uint)k1[i];
            dp += (int)(signed char)(a) * (int)(signed char)(b)
                + (int)(signed char)(a >> 8) * (int)(signed char)(b >> 8)
                + (int)(signed char)(a >> 16) * (int)(signed char)(b >> 16)
                + (int)(signed char)(a >> 24) * (int)(signed char)(b >> 24);
        }
#endif

        const float ksc = h2f((ushort)(scp & 0xffff));
        const float vsc = h2f((ushort)(scp >> 16));
        const float sc = (float)dp * ksc * qs6;

        float mxv = sc;
        mxv = fmaxf(mxv, __shfl_xor(mxv, 4));
        mxv = fmaxf(mxv, __shfl_xor(mxv, 8));
        mxv = fmaxf(mxv, __shfl_xor(mxv, 16));
        mxv = fmaxf(mxv, __shfl_xor(mxv, 32));
        const float e = __expf(sc - mxv);
        float sm = e;
        sm += __shfl_xor(sm, 4);
        sm += __shfl_xor(sm, 8);
        sm += __shfl_xor(sm, 16);
        sm += __shfl_xor(sm, 32);
        const float wgt = e * vsc / sm;

        float a0 = 0.f, a1 = 0.f;
#pragma unroll
        for (int j = 0; j < KNBR; ++j) {
            const float w2 = __shfl(wgt, j * 4 + h2v);
            const ushort u = vsh[j];
            a0 += w2 * (float)(signed char)(u & 0xff);
            a1 += w2 * (float)(signed char)(u >> 8);
        }
        // write row into swizzled LDS A-tile (normal channel order)
        const int row = wid * 8 + p;
        const int s0 = cb >> 3, s1 = (cb + 16) >> 3;
        ldsA[(row * 16 + (s0 ^ (row & 7))) * 8 + (cb & 7)] = f2b(a0);
        ldsA[(row * 16 + (s1 ^ (row & 7))) * 8 + ((cb + 16) & 7)] = f2b(a1);
    }
    __syncthreads();

    // ---- output projection phase: 64x128 tile. Wave wid: rows wr..wr+15, cols wc..wc+63
    const int fr = lane & 15, kb = lane >> 4;
    const int wr = (wid & 3) * 16, wc = (wid >> 2) * 64;

    floatx4 acc[4];
#pragma unroll
    for (int j = 0; j < 4; ++j) acc[j] = (floatx4){0.f, 0.f, 0.f, 0.f};

#pragma unroll
    for (int kkk = 0; kkk < 4; ++kkk) {
        const int slot = kkk * 4 + kb;
        const int arow = wr + fr;
        short8 af = *(const short8*)(ldsA + ((arow * 16 + (slot ^ (arow & 7))) * 8));
        short8 bf[4];
#pragma unroll
        for (int j = 0; j < 4; ++j) {
            const int brow = wc + j * 16 + fr;
            bf[j] = *(const short8*)(ldsW + ((brow * 16 + (slot ^ (brow & 7))) * 8));
        }
#pragma unroll
        for (int j = 0; j < 4; ++j)
            acc[j] = __builtin_amdgcn_mfma_f32_16x16x32_bf16(af, bf[j], acc[j], 0, 0, 0);
    }

#pragma unroll
    for (int j = 0; j < 4; ++j) {
        const int col = wc + j * 16 + fr;
        const float bv = bias[col];
#pragma unroll
        for (int r = 0; r < 4; ++r) {
            const int n = p0 + wr + kb * 4 + r;
            out[(size_t)n * 128 + col] = acc[j][r] + bv;
        }
    }
}

extern "C" void kernel_launch(void* const* d_in, const int* in_sizes, int n_in,
                              void* d_out, int out_size, void* d_ws, size_t ws_size,
                              hipStream_t stream)
{
    const float* feats = (const float*)d_in[0];
    const int*   knn   = (const int*)d_in[2];
    const float* Wq    = (const float*)d_in[3];
    const float* Wk    = (const float*)d_in[4];
    const float* Wv    = (const float*)d_in[5];
    const float* Wo    = (const float*)d_in[6];
    const float* bo    = (const float*)d_in[7];
    float* out = (float*)d_out;

    ushort* feats_b = (ushort*)d_ws;                                   // N*128 ushort
    unsigned char* q8  = (unsigned char*)(feats_b + (size_t)NPTS * C); // N*128 B
    unsigned char* kv8 = q8 + (size_t)NPTS * 128;                      // N*256 B
    ushort* scpack = (ushort*)(kv8 + (size_t)NPTS * 256);              // N*2 ushort
    float* qscale  = (float*)(scpack + (size_t)NPTS * 2);              // N floats
    ushort* wq_b   = (ushort*)(qscale + (size_t)NPTS);                 // 16384 each
    ushort* wk_b   = wq_b + 16384;
    ushort* wv_b   = wk_b + 16384;
    ushort* wo_b   = wv_b + 16384;

    prep_all<<<2080, 256, 0, stream>>>(feats, Wq, Wk, Wv, Wo,
                                       feats_b, wq_b, wk_b, wv_b, wo_b);
    qkv_gemm<<<dim3(NPTS / 128, 3), 256, 0, stream>>>(feats_b, wq_b, wk_b, wv_b,
                                                      q8, kv8, scpack, qscale);
    fused_attn_out<<<NPTS / 64, 512, 0, stream>>>(q8, kv8, scpack, qscale, knn,
                                                  wo_b, bo, out);
}

// Round 12
// 48.402 us; speedup vs baseline: 1.3336x; 1.0223x over previous
//
#include <hip/hip_runtime.h>

#define NPTS 32768
#define C 128
#define KNBR 16

typedef __attribute__((ext_vector_type(8))) short short8;
typedef __attribute__((ext_vector_type(4))) float floatx4;
typedef __attribute__((ext_vector_type(4))) int intx4;

__device__ __forceinline__ ushort f2b(float f) {
    union { float f; uint u; } x; x.f = f;
    uint r = (x.u + 0x7fffu + ((x.u >> 16) & 1u)) >> 16;
    return (ushort)r;
}
__device__ __forceinline__ ushort f2h(float f) {
    union { _Float16 h; ushort u; } x; x.h = (_Float16)f; return x.u;
}
__device__ __forceinline__ float h2f(ushort u) {
    union { ushort u; _Float16 h; } x; x.u = u; return (float)x.h;
}

// ---------------- prep: feats -> bf16; weights -> fragment-contiguous bf16 (wfrag) ----------------
// wfrag unit u = colblk*256 + kk*64 + kb*16 + fr (16B units) holds bf16 of
// W[col=colblk*16+fr][k=(kk*4+kb)*8 .. +8]. B-load for (colblk,kk): lane reads unit
// colblk*256 + kk*64 + lane -> one coalesced 1KB wave load.
__global__ __launch_bounds__(256) void prep_all(
    const float* __restrict__ feats, const float* __restrict__ Wq,
    const float* __restrict__ Wk, const float* __restrict__ Wv,
    const float* __restrict__ Wo,
    ushort* __restrict__ feats_b, ushort* __restrict__ wfq,
    ushort* __restrict__ wfk, ushort* __restrict__ wfv, ushort* __restrict__ wfo)
{
    const int b = blockIdx.x, tid = threadIdx.x;
    if (b < 2048) {
        const size_t i = (size_t)b * 2048 + (size_t)tid * 8;
        float4 v0 = *(const float4*)(feats + i);
        float4 v1 = *(const float4*)(feats + i + 4);
        intx4 o;
        o.x = (int)((uint)f2b(v0.x) | ((uint)f2b(v0.y) << 16));
        o.y = (int)((uint)f2b(v0.z) | ((uint)f2b(v0.w) << 16));
        o.z = (int)((uint)f2b(v1.x) | ((uint)f2b(v1.y) << 16));
        o.w = (int)((uint)f2b(v1.z) | ((uint)f2b(v1.w) << 16));
        *(intx4*)(feats_b + i) = o;
        return;
    }
    const int wb = b - 2048;                 // 0..31
    const int wsel = wb >> 3;                // 0..3
    const int tg = (wb & 7) * 256 + tid;     // unit id 0..2047
    const int colblk = tg >> 8;
    const int rem = tg & 255;
    const int kk = rem >> 6, kb = (rem >> 4) & 3, fr = rem & 15;
    const int col = colblk * 16 + fr;
    const int kbase = (kk * 4 + kb) * 8;

    const float* src = (wsel == 0) ? Wq : (wsel == 1) ? Wk : (wsel == 2) ? Wv : Wo;
    ushort* dst = (wsel == 0) ? wfq : (wsel == 1) ? wfk : (wsel == 2) ? wfv : wfo;

    ushort tmp[8];
#pragma unroll
    for (int e = 0; e < 8; ++e) tmp[e] = f2b(src[(size_t)col * 128 + kbase + e]);
    intx4 o;
    o.x = (int)((uint)tmp[0] | ((uint)tmp[1] << 16));
    o.y = (int)((uint)tmp[2] | ((uint)tmp[3] << 16));
    o.z = (int)((uint)tmp[4] | ((uint)tmp[5] << 16));
    o.w = (int)((uint)tmp[6] | ((uint)tmp[7] << 16));
    *(intx4*)(dst + (size_t)tg * 8) = o;
}

// ---------------- QKV GEMM: grid (1024, 3), 32-row tiles, wave-count-first ----------------
// 12288 waves total. A: 8KB LDS (2 indep loads/thread). W: 8 coalesced wfrag wave-loads.
// Wave wid owns cols [wid*32, wid*32+32). int8 word layout (head-pure, attn-compatible):
// word w = wid*8 + (fr>>1), bytes {c, c+16, c+1, c+17}, c = wid*32 + (fr&~1).
__global__ __launch_bounds__(256) void qkv_gemm(
    const ushort* __restrict__ A,
    const ushort* __restrict__ wfq, const ushort* __restrict__ wfk,
    const ushort* __restrict__ wfv,
    unsigned char* __restrict__ q8, unsigned char* __restrict__ kv8,
    ushort* __restrict__ scpack, float* __restrict__ qscale)
{
    __shared__ ushort ldsA[32 * 128];     // 8 KB
    __shared__ float rmax[4][32];
    const int tid = threadIdx.x, lane = tid & 63, wid = tid >> 6;
    const int r0 = blockIdx.x * 32, sel = blockIdx.y;
    const ushort* WF = (sel == 0) ? wfq : (sel == 1) ? wfk : wfv;

    // stage A: 512 16B units, 2 per thread, independent
#pragma unroll
    for (int it = 0; it < 2; ++it) {
        const int f = it * 256 + tid;
        const int row = f >> 4, slot = f & 15;
        intx4 v = *(const intx4*)(A + (size_t)r0 * 128 + (size_t)f * 8);
        *(intx4*)(ldsA + ((row * 16 + (slot ^ (row & 7))) * 8)) = v;
    }
    __syncthreads();

    const int fr = lane & 15, kb = lane >> 4;

    short8 af[2][4];
#pragma unroll
    for (int i = 0; i < 2; ++i)
#pragma unroll
        for (int kk = 0; kk < 4; ++kk) {
            const int row = i * 16 + fr;
            const int slot = kk * 4 + kb;
            af[i][kk] = *(const short8*)(ldsA + ((row * 16 + (slot ^ (row & 7))) * 8));
        }

    floatx4 acc[2][2];
#pragma unroll
    for (int i = 0; i < 2; ++i)
#pragma unroll
        for (int j = 0; j < 2; ++j) acc[i][j] = (floatx4){0.f, 0.f, 0.f, 0.f};

#pragma unroll
    for (int kk = 0; kk < 4; ++kk) {
        short8 bf[2];
#pragma unroll
        for (int j = 0; j < 2; ++j)
            bf[j] = *(const short8*)(WF + ((size_t)(wid * 2 + j) * 256 + kk * 64 + lane) * 8);
#pragma unroll
        for (int i = 0; i < 2; ++i)
#pragma unroll
            for (int j = 0; j < 2; ++j)
                acc[i][j] = __builtin_amdgcn_mfma_f32_16x16x32_bf16(af[i][kk], bf[j], acc[i][j], 0, 0, 0);
    }

    // per-row absmax over wave's 32 cols, then cross-wave via LDS
    float mx[2][4];
#pragma unroll
    for (int i = 0; i < 2; ++i)
#pragma unroll
        for (int r = 0; r < 4; ++r) {
            float m = fmaxf(fabsf(acc[i][0][r]), fabsf(acc[i][1][r]));
            m = fmaxf(m, __shfl_xor(m, 1));
            m = fmaxf(m, __shfl_xor(m, 2));
            m = fmaxf(m, __shfl_xor(m, 4));
            m = fmaxf(m, __shfl_xor(m, 8));
            mx[i][r] = m;
        }
    if (fr == 0) {
#pragma unroll
        for (int i = 0; i < 2; ++i)
#pragma unroll
            for (int r = 0; r < 4; ++r)
                rmax[wid][i * 16 + kb * 4 + r] = mx[i][r];
    }
    __syncthreads();

    const int boff = (wid * 8 + (fr >> 1)) * 4;
#pragma unroll
    for (int i = 0; i < 2; ++i)
#pragma unroll
        for (int r = 0; r < 4; ++r) {
            const int lr = i * 16 + kb * 4 + r;
            const int nn = r0 + lr;
            float comb = fmaxf(rmax[0][lr], rmax[1][lr]);
            comb = fmaxf(comb, rmax[2][lr]);
            comb = fmaxf(comb, rmax[3][lr]);
            comb = fmaxf(comb, 1e-20f);
            const float qs = 127.f / comb;
            int b0 = __float2int_rn(acc[i][0][r] * qs);   // col wid*32 + fr
            int b1 = __float2int_rn(acc[i][1][r] * qs);   // col wid*32 + fr + 16
            uint u16 = (uint)(b0 & 0xff) | ((uint)(b1 & 0xff) << 8);
            uint o16 = __shfl_xor(u16, 1);
            if (wid == 0 && fr == 0) {
                if (sel == 0)      qscale[nn] = comb * (1.f / 127.f);
                else if (sel == 1) scpack[(size_t)nn * 2]     = f2h(comb * (1.f / 127.f));
                else               scpack[(size_t)nn * 2 + 1] = f2h(comb * (1.f / 127.f));
            }
            if (!(fr & 1)) {
                const uint word = u16 | (o16 << 16);
                if (sel == 0)      *(uint*)(q8  + (size_t)nn * 128 + boff) = word;
                else if (sel == 1) *(uint*)(kv8 + (size_t)nn * 256 + boff) = word;
                else               *(uint*)(kv8 + (size_t)nn * 256 + 128 + boff) = word;
            }
        }
}

// ---------------- attention: 1 wave/point, 8192 blocks (32768 waves) — proven fast ----------------
__global__ __launch_bounds__(256, 6) void attn_kernel(
    const unsigned char* __restrict__ q8, const unsigned char* __restrict__ kv8,
    const ushort* __restrict__ scpack, const float* __restrict__ qscale,
    const int* __restrict__ knn, ushort* __restrict__ attn_p)
{
    const int tid = threadIdx.x;
    const int lane = tid & 63;
    const int wp = __builtin_amdgcn_readfirstlane(tid >> 6);
    const int n = blockIdx.x * 4 + wp;

    const int kk = lane >> 2, h = lane & 3;
    const int nb4 = knn[(size_t)n * KNBR + kk];
    const int* kr = knn + (size_t)n * KNBR;

    const unsigned char* krow = kv8 + (size_t)nb4 * 256 + h * 32;
    intx4 k0 = *(const intx4*)(krow);
    intx4 k1 = *(const intx4*)(krow + 16);
    const unsigned char* qrow = q8 + (size_t)n * 128 + h * 32;
    intx4 qq0 = *(const intx4*)(qrow);
    intx4 qq1 = *(const intx4*)(qrow + 16);
    const uint scp = *(const uint*)(scpack + (size_t)nb4 * 2);

    ushort vsh[KNBR];
#pragma unroll
    for (int j = 0; j < KNBR; ++j) {
        const int nbv = kr[j];
        vsh[j] = *(const ushort*)(kv8 + (size_t)nbv * 256 + 128 + lane * 2);
    }

    const float qs6 = qscale[n] * 0.17677669529663687f;

    int dp = 0;
#if __has_builtin(__builtin_amdgcn_sdot4)
#pragma unroll
    for (int i = 0; i < 4; ++i) dp = __builtin_amdgcn_sdot4(qq0[i], k0[i], dp, false);
#pragma unroll
    for (int i = 0; i < 4; ++i) dp = __builtin_amdgcn_sdot4(qq1[i], k1[i], dp, false);
#else
#pragma unroll
    for (int i = 0; i < 4; ++i) {
        uint a = (uint)qq0[i], b = (uint)k0[i];
        dp += (int)(signed char)(a) * (int)(signed char)(b)
            + (int)(signed char)(a >> 8) * (int)(signed char)(b >> 8)
            + (int)(signed char)(a >> 16) * (int)(signed char)(b >> 16)
            + (int)(signed char)(a >> 24) * (int)(signed char)(b >> 24);
        a = (uint)qq1[i]; b = (uint)k1[i];
        dp += (int)(signed char)(a) * (int)(signed char)(b)
            + (int)(signed char)(a >> 8) * (int)(signed char)(b >> 8)
            + (int)(signed char)(a >> 16) * (int)(signed char)(b >> 16)
            + (int)(signed char)(a >> 24) * (int)(signed char)(b >> 24);
    }
#endif

    const float ksc = h2f((ushort)(scp & 0xffff));
    const float vsc = h2f((ushort)(scp >> 16));
    const float sc = (float)dp * ksc * qs6;

    float mxv = sc;
    mxv = fmaxf(mxv, __shfl_xor(mxv, 4));
    mxv = fmaxf(mxv, __shfl_xor(mxv, 8));
    mxv = fmaxf(mxv, __shfl_xor(mxv, 16));
    mxv = fmaxf(mxv, __shfl_xor(mxv, 32));
    const float e = __expf(sc - mxv);
    float sm = e;
    sm += __shfl_xor(sm, 4);
    sm += __shfl_xor(sm, 8);
    sm += __shfl_xor(sm, 16);
    sm += __shfl_xor(sm, 32);
    const float wgt = e * vsc / sm;

    const int h2v = lane >> 4;
    float a0 = 0.f, a1 = 0.f;
#pragma unroll
    for (int j = 0; j < KNBR; ++j) {
        const float w2 = __shfl(wgt, j * 4 + h2v);
        const ushort u = vsh[j];
        a0 += w2 * (float)(signed char)(u & 0xff);
        a1 += w2 * (float)(signed char)(u >> 8);
    }
    // normal channel order: c0 = 32*(lane>>4) + (lane&15), c1 = c0 + 16
    const int cb = 32 * (lane >> 4) + (lane & 15);
    attn_p[(size_t)n * 128 + cb]      = f2b(a0);
    attn_p[(size_t)n * 128 + cb + 16] = f2b(a1);
}

// ---------------- output projection: 1024 blocks (4096 waves), wfrag Wo ----------------
__global__ __launch_bounds__(256) void out_gemm(
    const ushort* __restrict__ A, const ushort* __restrict__ wfo,
    const float* __restrict__ bias, float* __restrict__ out)
{
    __shared__ ushort ldsA[32 * 128];     // 8 KB
    const int tid = threadIdx.x, lane = tid & 63, wid = tid >> 6;
    const int r0 = blockIdx.x * 32;

#pragma unroll
    for (int it = 0; it < 2; ++it) {
        const int f = it * 256 + tid;
        const int row = f >> 4, slot = f & 15;
        intx4 v = *(const intx4*)(A + (size_t)r0 * 128 + (size_t)f * 8);
        *(intx4*)(ldsA + ((row * 16 + (slot ^ (row & 7))) * 8)) = v;
    }
    __syncthreads();

    const int fr = lane & 15, kb = lane >> 4;

    short8 af[2][4];
#pragma unroll
    for (int i = 0; i < 2; ++i)
#pragma unroll
        for (int kk = 0; kk < 4; ++kk) {
            const int row = i * 16 + fr;
            const int slot = kk * 4 + kb;
            af[i][kk] = *(const short8*)(ldsA + ((row * 16 + (slot ^ (row & 7))) * 8));
        }

    floatx4 acc[2][2];
#pragma unroll
    for (int i = 0; i < 2; ++i)
#pragma unroll
        for (int j = 0; j < 2; ++j) acc[i][j] = (floatx4){0.f, 0.f, 0.f, 0.f};

#pragma unroll
    for (int kk = 0; kk < 4; ++kk) {
        short8 bf[2];
#pragma unroll
        for (int j = 0; j < 2; ++j)
            bf[j] = *(const short8*)(wfo + ((size_t)(wid * 2 + j) * 256 + kk * 64 + lane) * 8);
#pragma unroll
        for (int i = 0; i < 2; ++i)
#pragma unroll
            for (int j = 0; j < 2; ++j)
                acc[i][j] = __builtin_amdgcn_mfma_f32_16x16x32_bf16(af[i][kk], bf[j], acc[i][j], 0, 0, 0);
    }

#pragma unroll
    for (int j = 0; j < 2; ++j) {
        const int col = wid * 32 + j * 16 + fr;
        const float bv = bias[col];
#pragma unroll
        for (int i = 0; i < 2; ++i)
#pragma unroll
            for (int r = 0; r < 4; ++r) {
                const int n = r0 + i * 16 + kb * 4 + r;
                out[(size_t)n * 128 + col] = acc[i][j][r] + bv;
            }
    }
}

extern "C" void kernel_launch(void* const* d_in, const int* in_sizes, int n_in,
                              void* d_out, int out_size, void* d_ws, size_t ws_size,
                              hipStream_t stream)
{
    const float* feats = (const float*)d_in[0];
    const int*   knn   = (const int*)d_in[2];
    const float* Wq    = (const float*)d_in[3];
    const float* Wk    = (const float*)d_in[4];
    const float* Wv    = (const float*)d_in[5];
    const float* Wo    = (const float*)d_in[6];
    const float* bo    = (const float*)d_in[7];
    float* out = (float*)d_out;

    ushort* feats_b = (ushort*)d_ws;                                   // N*128 ushort
    ushort* attn_p  = feats_b + (size_t)NPTS * C;                      // N*128 ushort
    unsigned char* q8  = (unsigned char*)(attn_p + (size_t)NPTS * C);  // N*128 B
    unsigned char* kv8 = q8 + (size_t)NPTS * 128;                      // N*256 B
    ushort* scpack = (ushort*)(kv8 + (size_t)NPTS * 256);              // N*2 ushort
    float* qscale  = (float*)(scpack + (size_t)NPTS * 2);              // N floats
    ushort* wfq    = (ushort*)(qscale + (size_t)NPTS);                 // 16384 each
    ushort* wfk    = wfq + 16384;
    ushort* wfv    = wfk + 16384;
    ushort* wfo    = wfv + 16384;

    prep_all<<<2080, 256, 0, stream>>>(feats, Wq, Wk, Wv, Wo,
                                       feats_b, wfq, wfk, wfv, wfo);
    qkv_gemm<<<dim3(NPTS / 32, 3), 256, 0, stream>>>(feats_b, wfq, wfk, wfv,
                                                     q8, kv8, scpack, qscale);
    attn_kernel<<<NPTS / 4, 256, 0, stream>>>(q8, kv8, scpack, qscale, knn, attn_p);
    out_gemm<<<NPTS / 32, 256, 0, stream>>>(attn_p, wfo, bo, out);
}